// Round 1
// baseline (79.106 us; speedup 1.0000x reference)
//
#include <hip/hip_runtime.h>

#define E10 10
#define NN 1024
#define BB 8
#define ICH 16   // i-chunks for weight column-sum partials

// ---------------- Kernel A: S[b,j,e] partials = sum_i relu(W[b,i,j]*cw[e]+cb[e])
__global__ __launch_bounds__(256) void k_wsum(const float* __restrict__ W,
                                              const float* __restrict__ eww,
                                              const float* __restrict__ ewb,
                                              float* __restrict__ Spart) {
    const int t  = threadIdx.x;
    const int jt = blockIdx.x;   // 0..1  (512 j each)
    const int ic = blockIdx.y;   // 0..15 (64 rows each)
    const int b  = blockIdx.z;   // 0..7
    const int j0 = jt * 512 + t * 2;

    float cw[E10], cb[E10];
#pragma unroll
    for (int e = 0; e < E10; e++) { cw[e] = eww[e]; cb[e] = ewb[e]; }

    float acc0[E10], acc1[E10];
#pragma unroll
    for (int e = 0; e < E10; e++) { acc0[e] = 0.f; acc1[e] = 0.f; }

    const float* Wp = W + ((size_t)b * NN + (size_t)ic * 64) * NN + j0;
    for (int ii = 0; ii < 64; ii++) {
        float2 w = *(const float2*)Wp;
        Wp += NN;
#pragma unroll
        for (int e = 0; e < E10; e++) {
            acc0[e] += fmaxf(w.x * cw[e] + cb[e], 0.f);
            acc1[e] += fmaxf(w.y * cw[e] + cb[e], 0.f);
        }
    }
    float* Sp = Spart + ((size_t)(ic * BB + b) * NN + j0) * E10;
#pragma unroll
    for (int e = 0; e < E10; e++) { Sp[e] = acc0[e]; Sp[E10 + e] = acc1[e]; }
}

// ---------------- Kernel B: base = v_selected + v_weights ; emb1 = relu(base+nbp_b)
__global__ __launch_bounds__(256) void k_base(const float* __restrict__ Spart,
                                              const float* __restrict__ feat,
                                              const float* __restrict__ selw,
                                              const float* __restrict__ selb,
                                              const float* __restrict__ nbww,
                                              const float* __restrict__ nbwb,
                                              const float* __restrict__ nbpb,
                                              float* __restrict__ base,
                                              float* __restrict__ embA) {
    const int gid = blockIdx.x * 256 + threadIdx.x;   // 0..8191 == b*1024+n
    float S[E10];
#pragma unroll
    for (int e = 0; e < E10; e++) S[e] = 0.f;

    for (int ic = 0; ic < ICH; ic++) {
        const float2* p = (const float2*)(Spart + ((size_t)ic * 8192 + gid) * E10);
#pragma unroll
        for (int q = 0; q < 5; q++) {
            float2 v = p[q];
            S[2 * q]     += v.x;
            S[2 * q + 1] += v.y;
        }
    }
    const float f = feat[gid];
#pragma unroll
    for (int o = 0; o < E10; o++) {
        float vw = nbwb[o];
#pragma unroll
        for (int e = 0; e < E10; e++) vw += S[e] * nbww[o * E10 + e];
        const float bv = f * selw[o] + selb[o] + vw;
        base[(size_t)gid * E10 + o] = bv;
        embA[(size_t)gid * E10 + o] = fmaxf(bv + nbpb[o], 0.f);
    }
}

// ---------------- Kernel C: embOut = relu(base + nbp(A @ embIn))
__global__ __launch_bounds__(256) void k_iter(const float* __restrict__ A,
                                              const float* __restrict__ embIn,
                                              const float* __restrict__ base,
                                              const float* __restrict__ nbpw,
                                              const float* __restrict__ nbpb,
                                              float* __restrict__ embOut) {
    __shared__ float2 lds2[5 * NN];   // [e2][j] transposed, 40 KB
    const int t    = threadIdx.x;
    const int b    = blockIdx.y;
    const int lane = t & 63;
    const int wave = t >> 6;

    // stage emb[b] into LDS (transposed float2 layout)
    const float2* src = (const float2*)(embIn + (size_t)b * (NN * E10));
    for (int idx = t; idx < 5120; idx += 256) {
        const int j  = idx / 5;
        const int e2 = idx - j * 5;
        lds2[e2 * NN + j] = src[idx];
    }

    // preload this lane's nbp row (lane o<10 computes output channel o)
    float nw[E10];
    float pb;
    {
        const int o = (lane < E10) ? lane : 0;
#pragma unroll
        for (int e = 0; e < E10; e++) nw[e] = nbpw[o * E10 + e];
        pb = nbpb[o];
    }
    __syncthreads();

    const int i0 = blockIdx.x * 16 + wave * 4;
    const float* Ab = A + ((size_t)b * NN + i0) * NN;

    float acc[4][E10];
#pragma unroll
    for (int r = 0; r < 4; r++)
#pragma unroll
        for (int e = 0; e < E10; e++) acc[r][e] = 0.f;

    for (int k = 0; k < 16; k++) {
        const int j = lane + (k << 6);
        const float2 p0 = lds2[j];
        const float2 p1 = lds2[NN + j];
        const float2 p2 = lds2[2 * NN + j];
        const float2 p3 = lds2[3 * NN + j];
        const float2 p4 = lds2[4 * NN + j];
        const float a0 = Ab[j];
        const float a1 = Ab[NN + j];
        const float a2 = Ab[2 * NN + j];
        const float a3 = Ab[3 * NN + j];
#define ROWFMA(r, a)                                                   \
        acc[r][0] += (a) * p0.x; acc[r][1] += (a) * p0.y;              \
        acc[r][2] += (a) * p1.x; acc[r][3] += (a) * p1.y;              \
        acc[r][4] += (a) * p2.x; acc[r][5] += (a) * p2.y;              \
        acc[r][6] += (a) * p3.x; acc[r][7] += (a) * p3.y;              \
        acc[r][8] += (a) * p4.x; acc[r][9] += (a) * p4.y;
        ROWFMA(0, a0) ROWFMA(1, a1) ROWFMA(2, a2) ROWFMA(3, a3)
#undef ROWFMA
    }

    // butterfly reduce each accumulator over the 64 lanes
#pragma unroll
    for (int r = 0; r < 4; r++) {
#pragma unroll
        for (int e = 0; e < E10; e++) {
            float v = acc[r][e];
            v += __shfl_xor(v, 32);
            v += __shfl_xor(v, 16);
            v += __shfl_xor(v, 8);
            v += __shfl_xor(v, 4);
            v += __shfl_xor(v, 2);
            v += __shfl_xor(v, 1);
            acc[r][e] = v;
        }
    }

    if (lane < E10) {
#pragma unroll
        for (int r = 0; r < 4; r++) {
            float p = pb;
#pragma unroll
            for (int e = 0; e < E10; e++) p += acc[r][e] * nw[e];
            const size_t row = (size_t)b * NN + i0 + r;
            const float bs = base[row * E10 + lane];
            embOut[row * E10 + lane] = fmaxf(bs + p, 0.f);
        }
    }
}

// ---------------- Kernel D: sdot[b] = sum_o (qall(emb.sum(n)))[o] * qred_w[o]
__global__ __launch_bounds__(256) void k_sums(const float* __restrict__ emb,
                                              const float* __restrict__ qallw,
                                              const float* __restrict__ qallb,
                                              const float* __restrict__ qredw,
                                              float* __restrict__ sdot) {
    const int b = blockIdx.x;
    const int t = threadIdx.x;
    const int lane = t & 63, wave = t >> 6;
    float acc[E10];
#pragma unroll
    for (int e = 0; e < E10; e++) acc[e] = 0.f;
    for (int n = t; n < NN; n += 256) {
        const float* p = emb + ((size_t)b * NN + n) * E10;
#pragma unroll
        for (int e = 0; e < E10; e++) acc[e] += p[e];
    }
#pragma unroll
    for (int e = 0; e < E10; e++) {
        float v = acc[e];
        v += __shfl_xor(v, 32);
        v += __shfl_xor(v, 16);
        v += __shfl_xor(v, 8);
        v += __shfl_xor(v, 4);
        v += __shfl_xor(v, 2);
        v += __shfl_xor(v, 1);
        acc[e] = v;
    }
    __shared__ float lds[4][E10];
    if (lane == 0) {
#pragma unroll
        for (int e = 0; e < E10; e++) lds[wave][e] = acc[e];
    }
    __syncthreads();
    if (t == 0) {
        float S[E10];
#pragma unroll
        for (int e = 0; e < E10; e++)
            S[e] = lds[0][e] + lds[1][e] + lds[2][e] + lds[3][e];
        float sd = 0.f;
#pragma unroll
        for (int o = 0; o < E10; o++) {
            float se = qallb[o];
#pragma unroll
            for (int e = 0; e < E10; e++) se += S[e] * qallw[o * E10 + e];
            sd += se * qredw[o];
        }
        sdot[b] = sd;
    }
}

// ---------------- Kernel E: q_vals + emb copy to out
__global__ __launch_bounds__(256) void k_out(const float* __restrict__ emb,
                                             const float* __restrict__ qactw,
                                             const float* __restrict__ qactb,
                                             const float* __restrict__ qredw,
                                             const float* __restrict__ qredb,
                                             const float* __restrict__ sdot,
                                             float* __restrict__ out) {
    const int gid = blockIdx.x * 256 + threadIdx.x;   // 0..8191
    const int b = gid >> 10;
    float v[E10];
    const float2* p = (const float2*)(emb + (size_t)gid * E10);
#pragma unroll
    for (int q = 0; q < 5; q++) {
        float2 w = p[q];
        v[2 * q] = w.x;
        v[2 * q + 1] = w.y;
    }
    float qv = qredb[0] + sdot[b];
#pragma unroll
    for (int o = 0; o < E10; o++) {
        float pa = qactb[o];
#pragma unroll
        for (int e = 0; e < E10; e++) pa += v[e] * qactw[o * E10 + e];
        qv += pa * qredw[E10 + o];
    }
    out[gid] = qv;
    float* o2 = out + 8192 + (size_t)gid * E10;
#pragma unroll
    for (int e = 0; e < E10; e++) o2[e] = v[e];
}

extern "C" void kernel_launch(void* const* d_in, const int* in_sizes, int n_in,
                              void* d_out, int out_size, void* d_ws, size_t ws_size,
                              hipStream_t stream) {
    const float* features = (const float*)d_in[0];
    const float* weights  = (const float*)d_in[1];
    const float* adjacency= (const float*)d_in[2];
    const float* sel_w    = (const float*)d_in[3];
    const float* sel_b    = (const float*)d_in[4];
    const float* nbp_w    = (const float*)d_in[5];
    const float* nbp_b    = (const float*)d_in[6];
    const float* nbw_w    = (const float*)d_in[7];
    const float* nbw_b    = (const float*)d_in[8];
    const float* nbwew_w  = (const float*)d_in[9];
    const float* nbwew_b  = (const float*)d_in[10];
    const float* qred_w   = (const float*)d_in[11];
    const float* qred_b   = (const float*)d_in[12];
    const float* qall_w   = (const float*)d_in[13];
    const float* qall_b   = (const float*)d_in[14];
    const float* qact_w   = (const float*)d_in[15];
    const float* qact_b   = (const float*)d_in[16];
    float* out = (float*)d_out;
    float* ws  = (float*)d_ws;

    const size_t BNE = (size_t)BB * NN * E10;       // 81920
    float* Spart = ws;                               // ICH * BNE
    float* base  = ws + (size_t)ICH * BNE;           // BNE
    float* embA  = base + BNE;                       // BNE
    float* embB  = embA + BNE;                       // BNE
    float* sdot  = embB + BNE;                       // 8

    k_wsum<<<dim3(2, ICH, BB), 256, 0, stream>>>(weights, nbwew_w, nbwew_b, Spart);
    k_base<<<32, 256, 0, stream>>>(Spart, features, sel_w, sel_b, nbw_w, nbw_b, nbp_b,
                                   base, embA);
    k_iter<<<dim3(64, BB), 256, 0, stream>>>(adjacency, embA, base, nbp_w, nbp_b, embB);
    k_iter<<<dim3(64, BB), 256, 0, stream>>>(adjacency, embB, base, nbp_w, nbp_b, embA);
    k_sums<<<BB, 256, 0, stream>>>(embA, qall_w, qall_b, qred_w, sdot);
    k_out<<<32, 256, 0, stream>>>(embA, qact_w, qact_b, qred_w, qred_b, sdot, out);
}

// Round 2
// 72.986 us; speedup vs baseline: 1.0839x; 1.0839x over previous
//
#include <hip/hip_runtime.h>

#define E10 10
#define NN 1024
#define BB 8
#define ICH 16   // row-chunks (64 rows each) for weight column-sum partials

// ---------------- Kernel A: partial column sums of relu(W*cw+cb)
// grid (2 jt, 16 ic, 8 b), block 256. Thread: 4 cols (float4) x 32 rows.
// Two 32-row halves per block combined via LDS; h==0 stores.
__global__ __launch_bounds__(256) void k_wsum(const float* __restrict__ W,
                                              const float* __restrict__ eww,
                                              const float* __restrict__ ewb,
                                              float2* __restrict__ Spart) {
    const int t  = threadIdx.x;
    const int jt = blockIdx.x;   // 0..1
    const int ic = blockIdx.y;   // 0..15
    const int b  = blockIdx.z;   // 0..7
    const int tt = t & 127;
    const int h  = t >> 7;       // row-half
    const int j0 = jt * 512 + tt * 4;
    const int i0 = ic * 64 + h * 32;

    float cw[E10], cb[E10];
#pragma unroll
    for (int e = 0; e < E10; e++) { cw[e] = eww[e]; cb[e] = ewb[e]; }

    float acc[4][E10];
#pragma unroll
    for (int c = 0; c < 4; c++)
#pragma unroll
        for (int e = 0; e < E10; e++) acc[c][e] = 0.f;

    const float* bp = W + ((size_t)b * NN + i0) * NN + j0;

    auto comp4 = [&](const float4 w4) {
#pragma unroll
        for (int e = 0; e < E10; e++) {
            acc[0][e] += fmaxf(w4.x * cw[e] + cb[e], 0.f);
            acc[1][e] += fmaxf(w4.y * cw[e] + cb[e], 0.f);
            acc[2][e] += fmaxf(w4.z * cw[e] + cb[e], 0.f);
            acc[3][e] += fmaxf(w4.w * cw[e] + cb[e], 0.f);
        }
    };

    float4 bufA[8], bufB[8];
#pragma unroll
    for (int r = 0; r < 8; r++) bufA[r] = *(const float4*)(bp + (size_t)r * NN);
#pragma unroll
    for (int r = 0; r < 8; r++) bufB[r] = *(const float4*)(bp + (size_t)(8 + r) * NN);
#pragma unroll
    for (int r = 0; r < 8; r++) comp4(bufA[r]);
#pragma unroll
    for (int r = 0; r < 8; r++) bufA[r] = *(const float4*)(bp + (size_t)(16 + r) * NN);
#pragma unroll
    for (int r = 0; r < 8; r++) comp4(bufB[r]);
#pragma unroll
    for (int r = 0; r < 8; r++) bufB[r] = *(const float4*)(bp + (size_t)(24 + r) * NN);
#pragma unroll
    for (int r = 0; r < 8; r++) comp4(bufA[r]);
#pragma unroll
    for (int r = 0; r < 8; r++) comp4(bufB[r]);

    __shared__ float cmb[128][40];   // 20 KB
    if (h) {
#pragma unroll
        for (int c = 0; c < 4; c++)
#pragma unroll
            for (int e = 0; e < E10; e++) cmb[tt][c * E10 + e] = acc[c][e];
    }
    __syncthreads();
    if (!h) {
#pragma unroll
        for (int c = 0; c < 4; c++)
#pragma unroll
            for (int e = 0; e < E10; e++) acc[c][e] += cmb[tt][c * E10 + e];
        const size_t gid = (size_t)b * NN + j0;
#pragma unroll
        for (int e2 = 0; e2 < 5; e2++) {
            float2* Sp = Spart + ((size_t)(ic * 5 + e2) * 8192 + gid);
#pragma unroll
            for (int c = 0; c < 4; c++)
                Sp[c] = make_float2(acc[c][2 * e2], acc[c][2 * e2 + 1]);
        }
    }
}

// ---------------- Kernel B: merge partials; base = v_selected + v_weights; emb1
// grid 256 blocks x 256 threads; thread (g = t&31, m = t>>5) merges 2 chunks.
__global__ __launch_bounds__(256) void k_base(const float2* __restrict__ Spart,
                                              const float* __restrict__ feat,
                                              const float* __restrict__ selw,
                                              const float* __restrict__ selb,
                                              const float* __restrict__ nbww,
                                              const float* __restrict__ nbwb,
                                              const float* __restrict__ nbpb,
                                              float* __restrict__ base,
                                              float* __restrict__ embA) {
    const int t = threadIdx.x;
    const int g = t & 31;
    const int m = t >> 5;                 // 0..7
    const int gid = blockIdx.x * 32 + g;  // 0..8191

    float S[E10];
#pragma unroll
    for (int e = 0; e < E10; e++) S[e] = 0.f;

#pragma unroll
    for (int cc = 0; cc < 2; cc++) {
        const int ic = m * 2 + cc;
#pragma unroll
        for (int e2 = 0; e2 < 5; e2++) {
            float2 v = Spart[(size_t)(ic * 5 + e2) * 8192 + gid];
            S[2 * e2] += v.x;
            S[2 * e2 + 1] += v.y;
        }
    }

    __shared__ float lds[8][32][E10];
#pragma unroll
    for (int e = 0; e < E10; e++) lds[m][g][e] = S[e];
    __syncthreads();
    if (m == 0) {
#pragma unroll
        for (int mm = 1; mm < 8; mm++)
#pragma unroll
            for (int e = 0; e < E10; e++) S[e] += lds[mm][g][e];
        const float f = feat[gid];
#pragma unroll
        for (int o = 0; o < E10; o++) {
            float vw = nbwb[o];
#pragma unroll
            for (int e = 0; e < E10; e++) vw += S[e] * nbww[o * E10 + e];
            const float bv = f * selw[o] + selb[o] + vw;
            base[(size_t)gid * E10 + o] = bv;
            embA[(size_t)gid * E10 + o] = fmaxf(bv + nbpb[o], 0.f);
        }
    }
}

// ---------------- Kernel C: embOut = relu(base + nbp(A @ embIn))
// grid (64, 8), block 256. Wave: 4 rows (lane>>4), 16-way j split (lane&15).
__global__ __launch_bounds__(256) void k_iter(const float* __restrict__ A,
                                              const float* __restrict__ embIn,
                                              const float* __restrict__ base,
                                              const float* __restrict__ nbpw,
                                              const float* __restrict__ nbpb,
                                              float* __restrict__ embOut) {
    __shared__ float2 lds2[5 * NN];   // [e2][j], 40 KB
    const int t    = threadIdx.x;
    const int b    = blockIdx.y;
    const int lane = t & 63;
    const int wave = t >> 6;
    const int lg   = lane >> 4;   // row within wave's 4
    const int ll   = lane & 15;   // j-lane

    const float2* src = (const float2*)(embIn + (size_t)b * (NN * E10));
    for (int idx = t; idx < 5120; idx += 256) {
        const int j  = idx / 5;
        const int e2 = idx - j * 5;
        lds2[e2 * NN + j] = src[idx];
    }

    const int o = (ll < E10) ? ll : 0;
    float nw[E10];
    const float pb = nbpb[o];
#pragma unroll
    for (int e = 0; e < E10; e++) nw[e] = nbpw[o * E10 + e];
    __syncthreads();

    const int row = blockIdx.x * 16 + wave * 4 + lg;
    const float* Ar = A + ((size_t)b * NN + row) * NN;

    float acc[E10];
#pragma unroll
    for (int e = 0; e < E10; e++) acc[e] = 0.f;

    // k = 0..31: j = ll*2 + k*32 ; 4-deep A prefetch pipeline
    float2 abuf[4];
#pragma unroll
    for (int k = 0; k < 4; k++) abuf[k] = *(const float2*)(Ar + ll * 2 + k * 32);
#pragma unroll
    for (int kb = 0; kb < 8; kb++) {
        float2 anxt[4];
        if (kb < 7) {
#pragma unroll
            for (int k = 0; k < 4; k++)
                anxt[k] = *(const float2*)(Ar + ll * 2 + (kb * 4 + 4 + k) * 32);
        }
#pragma unroll
        for (int kk = 0; kk < 4; kk++) {
            const int jj = ll * 2 + (kb * 4 + kk) * 32;
            const float2 a = abuf[kk];
#pragma unroll
            for (int e2 = 0; e2 < 5; e2++) {
                const float4 q = *(const float4*)&lds2[e2 * NN + jj];
                acc[2 * e2]     += a.x * q.x + a.y * q.z;
                acc[2 * e2 + 1] += a.x * q.y + a.y * q.w;
            }
        }
        if (kb < 7) {
#pragma unroll
            for (int k = 0; k < 4; k++) abuf[k] = anxt[k];
        }
    }

    // reduce over the 16 j-lanes
#pragma unroll
    for (int e = 0; e < E10; e++) {
        float v = acc[e];
        v += __shfl_xor(v, 8);
        v += __shfl_xor(v, 4);
        v += __shfl_xor(v, 2);
        v += __shfl_xor(v, 1);
        acc[e] = v;
    }

    if (ll < E10) {
        float p = pb;
#pragma unroll
        for (int e = 0; e < E10; e++) p += acc[e] * nw[e];
        const size_t off = ((size_t)b * NN + row) * E10 + o;
        embOut[off] = fmaxf(base[off] + p, 0.f);
    }
}

// ---------------- Kernel D: sdot[b] = sum_o (qall(emb.sum(n)))[o] * qred_w[o]
__global__ __launch_bounds__(256) void k_sums(const float* __restrict__ emb,
                                              const float* __restrict__ qallw,
                                              const float* __restrict__ qallb,
                                              const float* __restrict__ qredw,
                                              float* __restrict__ sdot) {
    const int b = blockIdx.x;
    const int t = threadIdx.x;
    const int lane = t & 63, wave = t >> 6;
    float acc[E10];
#pragma unroll
    for (int e = 0; e < E10; e++) acc[e] = 0.f;
    for (int n = t; n < NN; n += 256) {
        const float* p = emb + ((size_t)b * NN + n) * E10;
#pragma unroll
        for (int e = 0; e < E10; e++) acc[e] += p[e];
    }
#pragma unroll
    for (int e = 0; e < E10; e++) {
        float v = acc[e];
        v += __shfl_xor(v, 32);
        v += __shfl_xor(v, 16);
        v += __shfl_xor(v, 8);
        v += __shfl_xor(v, 4);
        v += __shfl_xor(v, 2);
        v += __shfl_xor(v, 1);
        acc[e] = v;
    }
    __shared__ float lds[4][E10];
    if (lane == 0) {
#pragma unroll
        for (int e = 0; e < E10; e++) lds[wave][e] = acc[e];
    }
    __syncthreads();
    if (t == 0) {
        float S[E10];
#pragma unroll
        for (int e = 0; e < E10; e++)
            S[e] = lds[0][e] + lds[1][e] + lds[2][e] + lds[3][e];
        float sd = 0.f;
#pragma unroll
        for (int o = 0; o < E10; o++) {
            float se = qallb[o];
#pragma unroll
            for (int e = 0; e < E10; e++) se += S[e] * qallw[o * E10 + e];
            sd += se * qredw[o];
        }
        sdot[b] = sd;
    }
}

// ---------------- Kernel E: q_vals + emb copy to out
__global__ __launch_bounds__(256) void k_out(const float* __restrict__ emb,
                                             const float* __restrict__ qactw,
                                             const float* __restrict__ qactb,
                                             const float* __restrict__ qredw,
                                             const float* __restrict__ qredb,
                                             const float* __restrict__ sdot,
                                             float* __restrict__ out) {
    const int gid = blockIdx.x * 256 + threadIdx.x;   // 0..8191
    const int b = gid >> 10;
    float v[E10];
    const float2* p = (const float2*)(emb + (size_t)gid * E10);
#pragma unroll
    for (int q = 0; q < 5; q++) {
        float2 w = p[q];
        v[2 * q] = w.x;
        v[2 * q + 1] = w.y;
    }
    float qv = qredb[0] + sdot[b];
#pragma unroll
    for (int o = 0; o < E10; o++) {
        float pa = qactb[o];
#pragma unroll
        for (int e = 0; e < E10; e++) pa += v[e] * qactw[o * E10 + e];
        qv += pa * qredw[E10 + o];
    }
    out[gid] = qv;
    float* o2 = out + 8192 + (size_t)gid * E10;
#pragma unroll
    for (int e = 0; e < E10; e++) o2[e] = v[e];
}

extern "C" void kernel_launch(void* const* d_in, const int* in_sizes, int n_in,
                              void* d_out, int out_size, void* d_ws, size_t ws_size,
                              hipStream_t stream) {
    const float* features = (const float*)d_in[0];
    const float* weights  = (const float*)d_in[1];
    const float* adjacency= (const float*)d_in[2];
    const float* sel_w    = (const float*)d_in[3];
    const float* sel_b    = (const float*)d_in[4];
    const float* nbp_w    = (const float*)d_in[5];
    const float* nbp_b    = (const float*)d_in[6];
    const float* nbw_w    = (const float*)d_in[7];
    const float* nbw_b    = (const float*)d_in[8];
    const float* nbwew_w  = (const float*)d_in[9];
    const float* nbwew_b  = (const float*)d_in[10];
    const float* qred_w   = (const float*)d_in[11];
    const float* qred_b   = (const float*)d_in[12];
    const float* qall_w   = (const float*)d_in[13];
    const float* qall_b   = (const float*)d_in[14];
    const float* qact_w   = (const float*)d_in[15];
    const float* qact_b   = (const float*)d_in[16];
    float* out = (float*)d_out;
    float* ws  = (float*)d_ws;

    const size_t BNE = (size_t)BB * NN * E10;       // 81920
    float2* Spart = (float2*)ws;                     // ICH*5*8192 float2 = 5.24 MB
    float* base  = ws + (size_t)ICH * 5 * 8192 * 2;  // BNE
    float* embA  = base + BNE;                       // BNE
    float* embB  = embA + BNE;                       // BNE
    float* sdot  = embB + BNE;                       // 8

    k_wsum<<<dim3(2, ICH, BB), 256, 0, stream>>>(weights, nbwew_w, nbwew_b, Spart);
    k_base<<<256, 256, 0, stream>>>(Spart, features, sel_w, sel_b, nbw_w, nbw_b, nbp_b,
                                    base, embA);
    k_iter<<<dim3(64, BB), 256, 0, stream>>>(adjacency, embA, base, nbp_w, nbp_b, embB);
    k_iter<<<dim3(64, BB), 256, 0, stream>>>(adjacency, embB, base, nbp_w, nbp_b, embA);
    k_sums<<<BB, 256, 0, stream>>>(embA, qall_w, qall_b, qred_w, sdot);
    k_out<<<32, 256, 0, stream>>>(embA, qact_w, qact_b, qred_w, qred_b, sdot, out);
}